// Round 3
// baseline (63936.676 us; speedup 1.0000x reference)
//
#include <hip/hip_runtime.h>
#include <stdint.h>
#include <stddef.h>

typedef unsigned short u16;
typedef unsigned int u32;

#define HISTN 64
#define TGEN 193
#define STH 68     // h row stride (floats): 272B, 16B-aligned, spreads banks
#define STW1 68    // W1 row stride
#define STWIH 20   // W_ih row stride (80B, 16B-aligned)

// strides (elements)
#define S_NOISE 2048
#define S_HIST  192
#define S_GAP   386
#define S_OUT   771

__device__ __forceinline__ float b2f(u16 u){ return __uint_as_float(((u32)u)<<16); }
__device__ __forceinline__ u16 f2b(float f){ u32 u=__float_as_uint(f); return (u16)((u + 0x7fffu + ((u>>16)&1u))>>16); }
__device__ __forceinline__ float tanhf_(float x){
    x = fminf(fmaxf(x,-30.f),30.f);
    float e = __expf(2.f*x);
    return (e-1.f)/(e+1.f);
}
__device__ __forceinline__ float ldv(const void* p, size_t i, bool f32){
    return f32 ? ((const float*)p)[i] : b2f(((const u16*)p)[i]);
}
__device__ __forceinline__ void stv(void* p, size_t i, float v, bool f32){
    if (f32) ((float*)p)[i] = v; else ((u16*)p)[i] = f2b(v);
}
__device__ __forceinline__ float dot4(float4 a, float4 b){
    return a.x*b.x + a.y*b.y + a.z*b.z + a.w*b.w;
}

extern "C" __global__ void __launch_bounds__(1024)
lstm_gen_kernel(const void* __restrict__ noise, const void* __restrict__ hist_x,
                const void* __restrict__ gap, const void* __restrict__ pW_ih,
                const void* __restrict__ pW_hh, const void* __restrict__ pb_ih,
                const void* __restrict__ pb_hh, const void* __restrict__ pW1,
                const void* __restrict__ pb1, const void* __restrict__ pW2,
                const void* __restrict__ pb2, void* __restrict__ out)
{
    // LDS: h double-buffer, W1 rows, W_ih rows, x double-buffer, dp
    __shared__ __align__(16) float hA[32*STH];
    __shared__ __align__(16) float hB[32*STH];
    __shared__ __align__(16) float w1l[64*STW1];
    __shared__ __align__(16) float wihl[256*STWIH];
    __shared__ __align__(16) float xA[32*16];
    __shared__ __align__(16) float xB[32*16];
    __shared__ float dpl[32];

    const int tid  = threadIdx.x;
    const int lane = tid & 63;
    const int w    = tid >> 6;
    const int gr   = w & 3;        // unit-group (16 units)
    const int bo   = w >> 2;       // batch octet
    const int g    = lane & 3;     // gate: 0=i 1=f 2=g 3=o
    const int q    = lane >> 2;    // unit within group
    const int u    = gr*16 + q;    // unit 0..63
    const int sg   = g*64 + u;     // global gate-row (gate-major storage)
    const int bbase = bo*8;
    const bool isx = (tid < 32);
    const int batch0 = blockIdx.x * 32;

    // ---- dtype detection (uniform): bf16-decoding fp32 mantissa halves explodes ----
    bool f32 = false;
    {
        const u32* p = (const u32*)pW_hh;
        for (int i = 0; i < 64; i++) {
            u32 v = p[i];
            float a = b2f((u16)(v & 0xffffu));
            float b = b2f((u16)(v >> 16));
            if (!(fabsf(a) <= 0.5f) || !(fabsf(b) <= 0.5f)) f32 = true;
        }
    }

    // ---- stage LDS weights ----
    for (int i = tid; i < 256*12; i += 1024) {
        int s = i / 12, k = i - s*12;
        wihl[s*STWIH + k] = ldv(pW_ih, (size_t)s*12 + k, f32);
    }
    for (int i = tid; i < 64*64; i += 1024) {
        int j = i >> 6, k = i & 63;
        w1l[j*STW1 + k] = ldv(pW1, (size_t)j*64 + k, f32);
    }
    for (int i = tid; i < 32*64; i += 1024)
        hA[(i >> 6)*STH + (i & 63)] = 0.0f;

    // ---- per-lane persistent registers ----
    float w4_[16][4];                      // W_hh row (64 floats)
    if (f32) {
        const float4* wp = (const float4*)((const float*)pW_hh + (size_t)sg*64);
#pragma unroll
        for (int i = 0; i < 16; i++) {
            float4 v = wp[i];
            w4_[i][0]=v.x; w4_[i][1]=v.y; w4_[i][2]=v.z; w4_[i][3]=v.w;
        }
    } else {
#pragma unroll
        for (int i = 0; i < 16; i++)
#pragma unroll
            for (int j = 0; j < 4; j++)
                w4_[i][j] = b2f(((const u16*)pW_hh)[(size_t)sg*64 + i*4 + j]);
    }
    const float biasr = ldv(pb_ih, sg, f32) + ldv(pb_hh, sg, f32);
    const float w23l  = ldv(pW_ih, (size_t)sg*12 + 2, f32) + ldv(pW_ih, (size_t)sg*12 + 3, f32);
    const float b1j   = ldv(pb1, lane, f32);
    const float w2j   = ldv(pW2, lane, f32);
    const float b2v   = ldv(pb2, 0, f32);

    float c[8];
#pragma unroll
    for (int b = 0; b < 8; b++) c[b] = 0.0f;
    float dist = 0.0f, gd0 = 0.0f, gd1 = 0.0f;

    const size_t histB  = (size_t)(batch0 + tid) * S_HIST;
    const size_t noiseB = (size_t)(batch0 + tid) * S_NOISE;
    const size_t gapB   = (size_t)(batch0 + tid) * S_GAP;
    const size_t outB   = (size_t)(batch0 + tid) * S_OUT;

    // ---- preloop: x for step 0, out row 0 ----
    if (isx) {
        float v0 = ldv(hist_x, histB+0, f32);
        float v1 = ldv(hist_x, histB+1, f32);
        float v2 = ldv(hist_x, histB+2, f32);
        dist = v2;
        float* xw8 = xA + tid*16;
        xw8[0]=v0; xw8[1]=v1; xw8[2]=v2; xw8[3]=dist;
#pragma unroll
        for (int j = 0; j < 8; j++) xw8[4+j] = ldv(noise, noiseB + j, f32);
        stv(out, outB+0, v0, f32); stv(out, outB+1, v1, f32); stv(out, outB+2, v2, f32);
    }
    __syncthreads();

    float* hb_r = hA; float* hb_w = hB;
    float* xb_r = xA; float* xb_w = xB;

    // GEMM phase A: acc = bias + W_ih·x + W_hh·h  (weights in regs, x/h uniform reads)
    auto gemm = [&](const float* hb, const float* xb, float (&acc)[8]) {
        const float4* wip = (const float4*)&wihl[sg*STWIH];
        float4 wi0 = wip[0], wi1 = wip[1], wi2 = wip[2];
#pragma unroll
        for (int b = 0; b < 8; b++) {
            const float4* xp = (const float4*)&xb[(bbase+b)*16];
            float a = biasr;
            a += dot4(wi0, xp[0]) + dot4(wi1, xp[1]) + dot4(wi2, xp[2]);
            const float4* hp = (const float4*)&hb[(bbase+b)*STH];
#pragma unroll
            for (int kc = 0; kc < 16; kc++) {
                float4 hv = hp[kc];
                a += w4_[kc][0]*hv.x + w4_[kc][1]*hv.y + w4_[kc][2]*hv.z + w4_[kc][3]*hv.w;
            }
            acc[b] = a;
        }
    };

    // activations + h store (quad shuffle): lane g==1 owns c,h
    auto act_store = [&](float (&acc)[8], float* hw) {
#pragma unroll
        for (int b = 0; b < 8; b++) {
            float xs = (g == 2) ? acc[b] : 0.5f*acc[b];
            float T  = tanhf_(xs);
            float a  = (g == 2) ? T : __builtin_fmaf(T, 0.5f, 0.5f);  // tanh or sigmoid
            float o2 = __shfl_xor(a, 2);       // lane1<-sig(o), lane0/2: partner for P
            float pr = a * o2;                 // lanes 0,2: P = sig(i)*tanh(g)
            float p1 = __shfl_xor(pr, 1);      // lane1 <- P
            if (g == 1) {
                float cn = a * c[b] + p1;      // sig(f)*c + P
                c[b] = cn;
                hw[(bbase+b)*STH + u] = o2 * tanhf_(cn);
            }
        }
    };

    // MLP head (gen): lane=j, wave covers 2 batches; writes dpl
    auto head = [&](const float* hb) {
        float m0 = b1j, m1 = b1j;
        const int hb0 = bbase + gr*2;
        const float4* w1p = (const float4*)&w1l[lane*STW1];
        const float4* h0p = (const float4*)&hb[hb0*STH];
        const float4* h1p = (const float4*)&hb[(hb0+1)*STH];
#pragma unroll
        for (int kc = 0; kc < 16; kc++) {
            float4 wv = w1p[kc];
            m0 += dot4(wv, h0p[kc]);
            m1 += dot4(wv, h1p[kc]);
        }
        float t0 = w2j * tanhf_(m0);
        float t1 = w2j * tanhf_(m1);
#pragma unroll
        for (int s = 1; s < 64; s <<= 1) {
            t0 += __shfl_xor(t0, s);
            t1 += __shfl_xor(t1, s);
        }
        if (lane < 2) {
            float sv = (lane == 0) ? t0 : t1;
            dpl[hb0 + lane] = 24.0f * tanhf_(sv + b2v);
        }
    };

    // ---- conditioning: 64 steps, 1 barrier each ----
#pragma unroll 1
    for (int t = 0; t < HISTN; t++) {
        float pf0=0.f, pf1=0.f, pf2=0.f, pfn[8];
#pragma unroll
        for (int j = 0; j < 8; j++) pfn[j] = 0.f;
        if (isx) {  // prefetch t+1 (or gen step 0 inputs)
            if (t < 63) {
                pf0 = ldv(hist_x, histB + (size_t)(t+1)*3 + 0, f32);
                pf1 = ldv(hist_x, histB + (size_t)(t+1)*3 + 1, f32);
                pf2 = ldv(hist_x, histB + (size_t)(t+1)*3 + 2, f32);
#pragma unroll
                for (int j = 0; j < 8; j++) pfn[j] = ldv(noise, noiseB + (size_t)(t+1)*8 + j, f32);
            } else {
                pf0 = ldv(gap, gapB+0, f32);
                pf1 = ldv(gap, gapB+1, f32);
#pragma unroll
                for (int j = 0; j < 8; j++) pfn[j] = ldv(noise, noiseB + (size_t)HISTN*8 + j, f32);
            }
        }
        float acc[8];
        gemm(hb_r, xb_r, acc);
        act_store(acc, hb_w);
        if (isx) {
            float* xw8 = xb_w + tid*16;
            if (t < 63) {
                dist += pf2;
                xw8[0]=pf0; xw8[1]=pf1; xw8[2]=pf2; xw8[3]=dist;
#pragma unroll
                for (int j = 0; j < 8; j++) xw8[4+j] = pfn[j];
                stv(out, outB + (size_t)(t+1)*3 + 0, pf0, f32);
                stv(out, outB + (size_t)(t+1)*3 + 1, pf1, f32);
                stv(out, outB + (size_t)(t+1)*3 + 2, pf2, f32);
            } else {  // hand off to gen step 0
                xw8[0]=pf0; xw8[1]=pf1; xw8[2]=0.f; xw8[3]=dist;
#pragma unroll
                for (int j = 0; j < 8; j++) xw8[4+j] = pfn[j];
                gd0 = pf0; gd1 = pf1;
            }
        }
        __syncthreads();
        float* tmp;
        tmp = hb_r; hb_r = hb_w; hb_w = tmp;
        tmp = xb_r; xb_r = xb_w; xb_w = tmp;
    }

    // ---- generation: 193 steps, 2 barriers each ----
#pragma unroll 1
    for (int tg = 0; tg < TGEN; tg++) {
        float pf0=0.f, pf1=0.f, pfn[8];
#pragma unroll
        for (int j = 0; j < 8; j++) pfn[j] = 0.f;
        if (isx && tg < TGEN-1) {  // prefetch tg+1
            pf0 = ldv(gap, gapB + (size_t)(tg+1)*2 + 0, f32);
            pf1 = ldv(gap, gapB + (size_t)(tg+1)*2 + 1, f32);
            if (tg + 1 < TGEN-1) {
#pragma unroll
                for (int j = 0; j < 8; j++)
                    pfn[j] = ldv(noise, noiseB + (size_t)(HISTN+tg+1)*8 + j, f32);
            }
        }
        head(hb_r);                      // writes dpl (reads h_prev)
        float acc[8];
        gemm(hb_r, xb_r, acc);           // x[2]=0, x[3]=dist_old baked in
        __syncthreads();                 // dpl visible
#pragma unroll
        for (int b = 0; b < 8; b++)
            acc[b] += w23l * dpl[bbase+b];   // + (w2+w3)*dp
        act_store(acc, hb_w);
        if (isx) {
            float dpv = dpl[tid];
            dist += dpv;
            stv(out, outB + (size_t)(HISTN+tg)*3 + 0, gd0, f32);
            stv(out, outB + (size_t)(HISTN+tg)*3 + 1, gd1, f32);
            stv(out, outB + (size_t)(HISTN+tg)*3 + 2, dpv, f32);
            if (tg < TGEN-1) {
                float* xw8 = xb_w + tid*16;
                xw8[0]=pf0; xw8[1]=pf1; xw8[2]=0.f; xw8[3]=dist;
#pragma unroll
                for (int j = 0; j < 8; j++) xw8[4+j] = pfn[j];
                gd0 = pf0; gd1 = pf1;
            }
        }
        __syncthreads();                 // h_next + x_next ready
        float* tmp;
        tmp = hb_r; hb_r = hb_w; hb_w = tmp;
        tmp = xb_r; xb_r = xb_w; xb_w = tmp;
    }
}

extern "C" void kernel_launch(void* const* d_in, const int* in_sizes, int n_in,
                              void* d_out, int out_size, void* d_ws, size_t ws_size,
                              hipStream_t stream) {
    (void)in_sizes; (void)n_in; (void)d_ws; (void)ws_size; (void)out_size;
    lstm_gen_kernel<<<256, 1024, 0, stream>>>(
        d_in[0], d_in[1], d_in[2], d_in[3], d_in[4], d_in[5],
        d_in[6], d_in[7], d_in[8], d_in[9], d_in[10], d_out);
}

// Round 4
// 61816.022 us; speedup vs baseline: 1.0343x; 1.0343x over previous
//
#include <hip/hip_runtime.h>
#include <stddef.h>

#define HISTN 64
#define TGEN 193
#define STH 68     // h row stride (floats)
#define STW1 68    // W1 row stride
#define STWIH 20   // W_ih row stride
#define STX 20     // x row stride

// global strides (elements)
#define S_NOISE 2048
#define S_HIST  192
#define S_GAP   386
#define S_OUT   771

__device__ __forceinline__ float tanhf_(float x){
    x = fminf(fmaxf(x,-30.f),30.f);
    float e = __expf(2.f*x);
    return (e-1.f)/(e+1.f);
}
__device__ __forceinline__ float dot4(float4 a, float4 b){
    return a.x*b.x + a.y*b.y + a.z*b.z + a.w*b.w;
}

extern "C" __global__ void __launch_bounds__(1024, 4)
lstm_gen_kernel(const float* __restrict__ noise, const float* __restrict__ hist_x,
                const float* __restrict__ gap, const float* __restrict__ pW_ih,
                const float* __restrict__ pW_hh, const float* __restrict__ pb_ih,
                const float* __restrict__ pb_hh, const float* __restrict__ pW1,
                const float* __restrict__ pb1, const float* __restrict__ pW2,
                const float* __restrict__ pb2, float* __restrict__ out)
{
    __shared__ __align__(16) float hA[32*STH];
    __shared__ __align__(16) float hB[32*STH];
    __shared__ __align__(16) float w1l[64*STW1];
    __shared__ __align__(16) float wihl[256*STWIH];
    __shared__ __align__(16) float xA[32*STX];
    __shared__ __align__(16) float xB[32*STX];
    __shared__ float dpl[32];
    // Occupancy clamp: total LDS > 80 KB => exactly 1 block/CU, so the
    // backend has no 2-block/8-wave incentive to spill VGPRs (round-3 bug).
    __shared__ float pad_[5504];

    const int tid  = threadIdx.x;
    const int lane = tid & 63;
    const int w    = tid >> 6;
    const int gr   = w & 3;        // unit-group (16 units)
    const int bo   = w >> 2;       // batch octet
    const int g    = lane & 3;     // gate: 0=i 1=f 2=g 3=o
    const int q    = lane >> 2;    // unit within group
    const int u    = gr*16 + q;    // unit 0..63
    const int sg   = g*64 + u;     // gate-major row index
    const int bbase = bo*8;
    const bool isx = (tid < 32);   // x-producer lanes (1 per batch)
    const int batch0 = blockIdx.x * 32;

    for (int i = tid; i < 5504; i += 1024) pad_[i] = 0.0f;

    // ---- stage LDS weights ----
    for (int i = tid; i < 256*12; i += 1024) {
        int s = i / 12, k = i - s*12;
        wihl[s*STWIH + k] = pW_ih[i];
    }
    for (int i = tid; i < 64*64; i += 1024)
        w1l[(i >> 6)*STW1 + (i & 63)] = pW1[i];
    for (int i = tid; i < 32*64; i += 1024)
        hA[(i >> 6)*STH + (i & 63)] = 0.0f;

    // ---- per-lane persistent registers: one W_hh row ----
    float4 w4v[16];
    {
        const float4* wp = (const float4*)(pW_hh + (size_t)sg*64);
#pragma unroll
        for (int i = 0; i < 16; i++) w4v[i] = wp[i];
    }
    const float biasr = pb_ih[sg] + pb_hh[sg];
    const float w23l  = pW_ih[sg*12 + 2] + pW_ih[sg*12 + 3];
    const float b1j   = pb1[lane];
    const float w2j   = pW2[lane];
    const float b2v   = pb2[0];

    float c[8];
#pragma unroll
    for (int b = 0; b < 8; b++) c[b] = 0.0f;
    float dist = 0.0f;

    const size_t histB  = (size_t)(batch0 + tid) * S_HIST;
    const size_t noiseB = (size_t)(batch0 + tid) * S_NOISE;
    const size_t gapB   = (size_t)(batch0 + tid) * S_GAP;
    const size_t outB   = (size_t)(batch0 + tid) * S_OUT;

    // ---- preloop: x(0), out row 0 ----
    if (isx) {
        float v0 = hist_x[histB+0], v1 = hist_x[histB+1], v2 = hist_x[histB+2];
        dist = v2;
        float* xw8 = xA + tid*STX;
        xw8[0]=v0; xw8[1]=v1; xw8[2]=v2; xw8[3]=dist;
#pragma unroll
        for (int j = 0; j < 8; j++) xw8[4+j] = noise[noiseB + j];
        out[outB+0]=v0; out[outB+1]=v1; out[outB+2]=v2;
    }
    __syncthreads();

    float* hb_r = hA; float* hb_w = hB;
    float* xb_r = xA; float* xb_w = xB;

    // acc = bias + W_ih·x + W_hh·h  (weights in regs, x/h wave-uniform reads)
    auto gemm = [&](const float* hb, const float* xb, float (&acc)[8]) {
        const float4* wip = (const float4*)&wihl[sg*STWIH];
        float4 wi0 = wip[0], wi1 = wip[1], wi2 = wip[2];
#pragma unroll
        for (int b = 0; b < 8; b++) {
            const float4* xp = (const float4*)&xb[(bbase+b)*STX];
            float a = biasr + dot4(wi0, xp[0]) + dot4(wi1, xp[1]) + dot4(wi2, xp[2]);
            const float4* hp = (const float4*)&hb[(bbase+b)*STH];
#pragma unroll
            for (int kc = 0; kc < 16; kc++) {
                float4 hv = hp[kc];
                a += w4v[kc].x*hv.x + w4v[kc].y*hv.y + w4v[kc].z*hv.z + w4v[kc].w*hv.w;
            }
            acc[b] = a;
        }
    };

    // activations + h store via quad shuffles; lane g==1 owns c,h
    auto act_store = [&](float (&acc)[8], float* hw) {
#pragma unroll
        for (int b = 0; b < 8; b++) {
            float xs = (g == 2) ? acc[b] : 0.5f*acc[b];
            float T  = tanhf_(xs);
            float a  = (g == 2) ? T : __builtin_fmaf(T, 0.5f, 0.5f);
            float o2 = __shfl_xor(a, 2);
            float pr = a * o2;                 // g=0: sig(i)*tanh(g)
            float p1 = __shfl_xor(pr, 1);
            if (g == 1) {
                float cn = a * c[b] + p1;      // sig(f)*c + P
                c[b] = cn;
                hw[(bbase+b)*STH + u] = o2 * tanhf_(cn);
            }
        }
    };

    // MLP head (gen): lane=j, each wave covers 2 batches; writes dpl
    auto head = [&](const float* hb) {
        float m0 = b1j, m1 = b1j;
        const int hb0 = bbase + gr*2;
        const float4* w1p = (const float4*)&w1l[lane*STW1];
        const float4* h0p = (const float4*)&hb[hb0*STH];
        const float4* h1p = (const float4*)&hb[(hb0+1)*STH];
#pragma unroll
        for (int kc = 0; kc < 16; kc++) {
            float4 wv = w1p[kc];
            m0 += dot4(wv, h0p[kc]);
            m1 += dot4(wv, h1p[kc]);
        }
        float t0 = w2j * tanhf_(m0);
        float t1 = w2j * tanhf_(m1);
#pragma unroll
        for (int s = 1; s < 64; s <<= 1) {
            t0 += __shfl_xor(t0, s);
            t1 += __shfl_xor(t1, s);
        }
        if (lane < 2) {
            float sv = (lane == 0) ? t0 : t1;
            dpl[hb0 + lane] = 24.0f * tanhf_(sv + b2v);
        }
    };

    // ---- conditioning: 64 steps, 1 barrier each ----
#pragma unroll 1
    for (int t = 0; t < HISTN; t++) {
        if (isx) {  // produce x(t+1) straight into write buffer (no live regs across gemm)
            float* xw8 = xb_w + tid*STX;
            if (t < 63) {
                float pf0 = hist_x[histB + (size_t)(t+1)*3 + 0];
                float pf1 = hist_x[histB + (size_t)(t+1)*3 + 1];
                float pf2 = hist_x[histB + (size_t)(t+1)*3 + 2];
                dist += pf2;
                xw8[0]=pf0; xw8[1]=pf1; xw8[2]=pf2; xw8[3]=dist;
#pragma unroll
                for (int j = 0; j < 8; j++) xw8[4+j] = noise[noiseB + (size_t)(t+1)*8 + j];
                out[outB + (size_t)(t+1)*3 + 0] = pf0;
                out[outB + (size_t)(t+1)*3 + 1] = pf1;
                out[outB + (size_t)(t+1)*3 + 2] = pf2;
            } else {  // hand off to gen step 0: x=[gd, dp=0, dist_old, nz]
                xw8[0] = gap[gapB + 0];
                xw8[1] = gap[gapB + 1];
                xw8[2] = 0.f; xw8[3] = dist;
#pragma unroll
                for (int j = 0; j < 8; j++) xw8[4+j] = noise[noiseB + (size_t)HISTN*8 + j];
            }
        }
        float acc[8];
        gemm(hb_r, xb_r, acc);
        act_store(acc, hb_w);
        __syncthreads();
        float* tmp;
        tmp = hb_r; hb_r = hb_w; hb_w = tmp;
        tmp = xb_r; xb_r = xb_w; xb_w = tmp;
    }

    // ---- generation: 193 steps, 2 barriers each ----
    // gemm consumes x with x[2]=0, x[3]=dist_old; dp correction folded in after
    // barrier via acc += (Wih[:,2]+Wih[:,3]) * dp.
#pragma unroll 1
    for (int tg = 0; tg < TGEN; tg++) {
        if (isx && tg < TGEN-1) {  // produce dp-independent part of x(tg+1)
            float* xw8 = xb_w + tid*STX;
            xw8[0] = gap[gapB + (size_t)(tg+1)*2 + 0];
            xw8[1] = gap[gapB + (size_t)(tg+1)*2 + 1];
            xw8[2] = 0.f;
            if (tg < TGEN-2) {
#pragma unroll
                for (int j = 0; j < 8; j++)
                    xw8[4+j] = noise[noiseB + (size_t)(HISTN+tg+1)*8 + j];
            } else {
#pragma unroll
                for (int j = 0; j < 8; j++) xw8[4+j] = 0.f;
            }
        }
        head(hb_r);
        float acc[8];
        gemm(hb_r, xb_r, acc);
        __syncthreads();               // dpl visible
#pragma unroll
        for (int b = 0; b < 8; b++)
            acc[b] += w23l * dpl[bbase+b];
        act_store(acc, hb_w);
        if (isx) {
            float dpv = dpl[tid];
            dist += dpv;
            const float* xr = xb_r + tid*STX;
            out[outB + (size_t)(HISTN+tg)*3 + 0] = xr[0];
            out[outB + (size_t)(HISTN+tg)*3 + 1] = xr[1];
            out[outB + (size_t)(HISTN+tg)*3 + 2] = dpv;
            if (tg < TGEN-1) (xb_w + tid*STX)[3] = dist;
        }
        __syncthreads();               // h_next + x_next ready
        float* tmp;
        tmp = hb_r; hb_r = hb_w; hb_w = tmp;
        tmp = xb_r; xb_r = xb_w; xb_w = tmp;
    }

    // keep pad_ alive (never true: pad_ is all zeros)
    if (pad_[tid % 5504] != 0.0f) out[outB] = 1e30f;
}

extern "C" void kernel_launch(void* const* d_in, const int* in_sizes, int n_in,
                              void* d_out, int out_size, void* d_ws, size_t ws_size,
                              hipStream_t stream) {
    (void)in_sizes; (void)n_in; (void)d_ws; (void)ws_size; (void)out_size;
    lstm_gen_kernel<<<256, 1024, 0, stream>>>(
        (const float*)d_in[0], (const float*)d_in[1], (const float*)d_in[2],
        (const float*)d_in[3], (const float*)d_in[4], (const float*)d_in[5],
        (const float*)d_in[6], (const float*)d_in[7], (const float*)d_in[8],
        (const float*)d_in[9], (const float*)d_in[10], (float*)d_out);
}

// Round 6
// 6749.078 us; speedup vs baseline: 9.4734x; 9.1592x over previous
//
#include <hip/hip_runtime.h>
#include <stddef.h>

#define HISTN 64
#define TGEN 193
#define STH 68       // h row stride (floats), 16B-aligned
#define STW1 68      // W1 row stride

// global strides (elements)
#define S_NOISE 2048
#define S_HIST  192
#define S_GAP   386
#define S_OUT   771

__device__ __forceinline__ float tanhf_(float x){
    x = fminf(fmaxf(x,-30.f),30.f);
    float e = __expf(2.f*x);
    return (e-1.f)/(e+1.f);
}

// W_hh FMA over one float4 chunk, named registers wh0..wh15
#define KC(i) { float4 hv = hp[i]; \
    a += wh##i.x*hv.x + wh##i.y*hv.y + wh##i.z*hv.z + wh##i.w*hv.w; }

#define KC_ALL KC(0) KC(1) KC(2) KC(3) KC(4) KC(5) KC(6) KC(7) \
               KC(8) KC(9) KC(10) KC(11) KC(12) KC(13) KC(14) KC(15)

// gemm + activations + h-store for this thread's gate-row over 8 batches.
// DPB: per-batch dp expression (0.0f in conditioning phase).
#define GEMM_ACT(hbr, xgr, xnr, hbw, DPB) do {                              \
    _Pragma("unroll")                                                        \
    for (int b = 0; b < 8; b++) {                                            \
        const float4* hp  = (const float4*)&(hbr)[(bbase+b)*STH];            \
        const float4* xgp = (const float4*)&(xgr)[(bbase+b)*8];              \
        const float4* xnp = (const float4*)&(xnr)[(bbase+b)*8];              \
        float4 xv = xgp[0];                                                  \
        float4 n0 = xnp[0];                                                  \
        float4 n1 = xnp[1];                                                  \
        float a = biasr + w23l*(DPB);                                        \
        a += wi0.x*xv.x + wi0.y*xv.y + wi0.z*xv.z + wi0.w*xv.w;              \
        a += wi1.x*n0.x + wi1.y*n0.y + wi1.z*n0.z + wi1.w*n0.w;              \
        a += wi2.x*n1.x + wi2.y*n1.y + wi2.z*n1.z + wi2.w*n1.w;              \
        KC_ALL                                                               \
        float xs = (g == 2) ? a : 0.5f*a;                                    \
        float T  = tanhf_(xs);                                               \
        float av = (g == 2) ? T : __builtin_fmaf(T, 0.5f, 0.5f);             \
        float o2 = __shfl_xor(av, 2);                                        \
        float pr = av * o2;                                                  \
        float p1 = __shfl_xor(pr, 1);                                        \
        if (g == 1) {                                                        \
            float cn = av*c[b] + p1;                                         \
            c[b] = cn;                                                       \
            (hbw)[(bbase+b)*STH + u] = o2 * tanhf_(cn);                      \
        }                                                                    \
    }                                                                        \
} while (0)

extern "C" __global__ void __launch_bounds__(512)
__attribute__((amdgpu_waves_per_eu(4, 4)))
lstm_gen_kernel(const float* __restrict__ noise, const float* __restrict__ hist_x,
                const float* __restrict__ gap, const float* __restrict__ pW_ih,
                const float* __restrict__ pW_hh, const float* __restrict__ pb_ih,
                const float* __restrict__ pb_hh, const float* __restrict__ pW1,
                const float* __restrict__ pb1, const float* __restrict__ pW2,
                const float* __restrict__ pb2, float* __restrict__ out)
{
    __shared__ __align__(16) float hA[16*STH];
    __shared__ __align__(16) float hB[16*STH];
    __shared__ __align__(16) float w1l[64*STW1];
    __shared__ __align__(16) float xgA[16*8];
    __shared__ __align__(16) float xgB[16*8];
    __shared__ __align__(16) float xnA[16*8];
    __shared__ __align__(16) float xnB[16*8];
    __shared__ float dpl[16];

    const int tid  = threadIdx.x;
    const int lane = tid & 63;
    const int w    = tid >> 6;        // 8 waves
    const int gr   = w & 3;           // unit-group (16 units)
    const int bo   = w >> 2;          // batch octet 0/1
    const int g    = lane & 3;        // gate 0=i 1=f 2=g 3=o
    const int q    = lane >> 2;       // unit in group
    const int u    = gr*16 + q;       // unit 0..63
    const int sg   = g*64 + u;        // gate-major row index
    const int bbase = bo*8;
    const int batch0 = blockIdx.x * 16;
    // producer roles — wave 0 only (round-5 bug: `tid>=32` matched waves 1..7
    // too, whose npb up to 239 wrote ~35KB past the LDS allocation -> GPU fault)
    const bool isg = (tid < 16);              // xg/out/dist producer, 1/batch
    const bool isn = (tid >= 32 && tid < 64); // noise producer, 2/batch

    // ---- stage W1 to LDS; zero h ----
    for (int i = tid; i < 64*64; i += 512)
        w1l[(i >> 6)*STW1 + (i & 63)] = pW1[i];
    for (int i = tid; i < 16*STH; i += 512) hA[i] = 0.0f;

    // ---- per-lane persistent weights (named regs -> guaranteed SROA) ----
    const float4* wp = (const float4*)(pW_hh + (size_t)sg*64);
    float4 wh0 = wp[0],  wh1 = wp[1],  wh2 = wp[2],  wh3 = wp[3];
    float4 wh4 = wp[4],  wh5 = wp[5],  wh6 = wp[6],  wh7 = wp[7];
    float4 wh8 = wp[8],  wh9 = wp[9],  wh10 = wp[10], wh11 = wp[11];
    float4 wh12 = wp[12], wh13 = wp[13], wh14 = wp[14], wh15 = wp[15];
    const float4* wip = (const float4*)(pW_ih + (size_t)sg*12);
    float4 wi0 = wip[0], wi1 = wip[1], wi2 = wip[2];
    const float biasr = pb_ih[sg] + pb_hh[sg];
    const float w23l  = wi0.z + wi0.w;   // W_ih cols 2,3 of this row
    const float b1j   = pb1[lane];
    const float w2j   = pW2[lane];
    const float b2v   = pb2[0];

    float c[8];
#pragma unroll
    for (int b = 0; b < 8; b++) c[b] = 0.0f;

    // ---- producer state ----
    float dist = 0.0f, pfa = 0.f, pfb = 0.f, pfc = 0.f;
    float4 pfn = {0.f, 0.f, 0.f, 0.f};
    const size_t histB = (size_t)(batch0 + tid) * S_HIST;
    const size_t gapB  = (size_t)(batch0 + tid) * S_GAP;
    const size_t outB  = (size_t)(batch0 + tid) * S_OUT;
    const int npb = (tid - 32) >> 1;          // noise batch (valid when isn)
    const int nph = tid & 1;                  // noise half
    const size_t noiseB = (size_t)(batch0 + (isn ? npb : 0)) * S_NOISE;

    // ---- preloop: step-0 buffers + step-1 prefetch ----
    if (isg) {
        float h0 = hist_x[histB+0], h1 = hist_x[histB+1], h2 = hist_x[histB+2];
        dist = h2;
        float* xw = xgA + tid*8;
        xw[0]=h0; xw[1]=h1; xw[2]=h2; xw[3]=dist;
        out[outB+0]=h0; out[outB+1]=h1; out[outB+2]=h2;
        pfa = hist_x[histB+3]; pfb = hist_x[histB+4]; pfc = hist_x[histB+5];
    }
    if (isn) {
        const float4* np = (const float4*)(noise + noiseB + nph*4);
        *(float4*)(xnA + npb*8 + nph*4) = np[0];
        pfn = np[2];                           // noise step 1
    }
    __syncthreads();

    float* hb_r = hA;  float* hb_w = hB;
    float* xg_r = xgA; float* xg_w = xgB;
    float* xn_r = xnA; float* xn_w = xnB;

    // ---- conditioning: 64 steps, 1 barrier each ----
#pragma unroll 1
    for (int t = 0; t < HISTN; t++) {
        if (isg) {
            float* xw = xg_w + tid*8;
            if (t < 63) {
                dist += pfc;
                xw[0]=pfa; xw[1]=pfb; xw[2]=pfc; xw[3]=dist;
                out[outB + (size_t)(t+1)*3 + 0] = pfa;
                out[outB + (size_t)(t+1)*3 + 1] = pfb;
                out[outB + (size_t)(t+1)*3 + 2] = pfc;
            } else {   // gen step 0: x=[gd0,gd1, dp-slot 0, dist_old]
                xw[0]=pfa; xw[1]=pfb; xw[2]=0.f; xw[3]=dist;
                out[outB + (size_t)HISTN*3 + 0] = pfa;
                out[outB + (size_t)HISTN*3 + 1] = pfb;
            }
            if (t <= 61) {
                pfa = hist_x[histB + (size_t)(t+2)*3 + 0];
                pfb = hist_x[histB + (size_t)(t+2)*3 + 1];
                pfc = hist_x[histB + (size_t)(t+2)*3 + 2];
            } else if (t == 62) {
                pfa = gap[gapB+0]; pfb = gap[gapB+1];
            } else {
                pfa = gap[gapB+2]; pfb = gap[gapB+3];
            }
        }
        if (isn) {
            *(float4*)(xn_w + npb*8 + nph*4) = pfn;
            pfn = *(const float4*)(noise + noiseB + (size_t)(t+2)*8 + nph*4);
        }
        GEMM_ACT(hb_r, xg_r, xn_r, hb_w, 0.0f);
        __syncthreads();
        float* tp;
        tp = hb_r; hb_r = hb_w; hb_w = tp;
        tp = xg_r; xg_r = xg_w; xg_w = tp;
        tp = xn_r; xn_r = xn_w; xn_w = tp;
    }

    // ---- generation: 193 steps, 2 barriers each ----
#pragma unroll 1
    for (int tg = 0; tg < TGEN; tg++) {
        // MLP head on h_prev: wave w covers batches 2w, 2w+1; lane = j
        {
            float m0 = b1j, m1 = b1j;
            const float4* w1p = (const float4*)&w1l[lane*STW1];
            const float4* h0p = (const float4*)&hb_r[(2*w)*STH];
            const float4* h1p = (const float4*)&hb_r[(2*w+1)*STH];
#pragma unroll
            for (int kc = 0; kc < 16; kc++) {
                float4 wv = w1p[kc];
                float4 a0 = h0p[kc];
                float4 a1 = h1p[kc];
                m0 += wv.x*a0.x + wv.y*a0.y + wv.z*a0.z + wv.w*a0.w;
                m1 += wv.x*a1.x + wv.y*a1.y + wv.z*a1.z + wv.w*a1.w;
            }
            float t0 = w2j * tanhf_(m0);
            float t1 = w2j * tanhf_(m1);
#pragma unroll
            for (int s = 1; s < 64; s <<= 1) {
                t0 += __shfl_xor(t0, s);
                t1 += __shfl_xor(t1, s);
            }
            if (lane < 2) {
                float sv = (lane == 0) ? t0 : t1;
                dpl[2*w + lane] = 24.0f * tanhf_(sv + b2v);
            }
        }
        __syncthreads();                       // B1: dpl visible

        GEMM_ACT(hb_r, xg_r, xn_r, hb_w, dpl[bbase+b]);

        if (isg) {
            float dpv = dpl[tid];
            dist += dpv;
            out[outB + (size_t)(HISTN+tg)*3 + 2] = dpv;
            if (tg < TGEN-1) {
                float* xw = xg_w + tid*8;
                xw[0]=pfa; xw[1]=pfb; xw[2]=0.f; xw[3]=dist;
                out[outB + (size_t)(HISTN+tg+1)*3 + 0] = pfa;
                out[outB + (size_t)(HISTN+tg+1)*3 + 1] = pfb;
                if (tg < TGEN-2) {
                    pfa = gap[gapB + (size_t)(tg+2)*2 + 0];
                    pfb = gap[gapB + (size_t)(tg+2)*2 + 1];
                }
            }
        }
        if (isn) {
            if (tg <= TGEN-3) {                // normal: write pfn, prefetch next
                *(float4*)(xn_w + npb*8 + nph*4) = pfn;
                if (tg <= TGEN-4)
                    pfn = *(const float4*)(noise + noiseB + (size_t)(HISTN+tg+2)*8 + nph*4);
            } else if (tg == TGEN-2) {         // last gen step reads zero noise
                float4 z = {0.f,0.f,0.f,0.f};
                *(float4*)(xn_w + npb*8 + nph*4) = z;
            }
        }
        __syncthreads();                       // B2: h/x next ready
        float* tp;
        tp = hb_r; hb_r = hb_w; hb_w = tp;
        tp = xg_r; xg_r = xg_w; xg_w = tp;
        tp = xn_r; xn_r = xn_w; xn_w = tp;
    }
}

extern "C" void kernel_launch(void* const* d_in, const int* in_sizes, int n_in,
                              void* d_out, int out_size, void* d_ws, size_t ws_size,
                              hipStream_t stream) {
    (void)in_sizes; (void)n_in; (void)d_ws; (void)ws_size; (void)out_size;
    lstm_gen_kernel<<<512, 512, 0, stream>>>(
        (const float*)d_in[0], (const float*)d_in[1], (const float*)d_in[2],
        (const float*)d_in[3], (const float*)d_in[4], (const float*)d_in[5],
        (const float*)d_in[6], (const float*)d_in[7], (const float*)d_in[8],
        (const float*)d_in[9], (const float*)d_in[10], (float*)d_out);
}